// Round 5
// baseline (197.827 us; speedup 1.0000x reference)
//
#include <hip/hip_runtime.h>
#include <math.h>

typedef float vf4 __attribute__((ext_vector_type(4)));
typedef float f32x4 __attribute__((ext_vector_type(4)));
typedef short bf16x8 __attribute__((ext_vector_type(8)));
typedef short short4v __attribute__((ext_vector_type(4)));
typedef int int2v __attribute__((ext_vector_type(2)));

constexpr int B = 2, T = 2048, E = 512, NH = 8, HD = 64;
constexpr int BH = B * NH;            // 16
constexpr int NT = BH * T;            // 32768
constexpr float SCALE = 0.125f;       // HD^-0.5

static __device__ __forceinline__ short f2bf(float f) {
  unsigned u = __float_as_uint(f);
  unsigned r = (u + 0x7fffu + ((u >> 16) & 1u)) >> 16;   // RNE
  return (short)r;
}
static __device__ __forceinline__ unsigned pk2bf(float a, float b) {
  unsigned lo = (unsigned)(unsigned short)f2bf(a);
  unsigned hi = (unsigned)(unsigned short)f2bf(b);
  return lo | (hi << 16);
}

// =====================================================================
// casts
// =====================================================================
__global__ __launch_bounds__(256) void cast_x_bf16(
    const float* __restrict__ x, short* __restrict__ xb)
{
  int idx = (blockIdx.x * 256 + threadIdx.x) * 4;
  vf4 v = *(const vf4*)&x[idx];
  short4v o;
  o[0] = f2bf(v[0]); o[1] = f2bf(v[1]); o[2] = f2bf(v[2]); o[3] = f2bf(v[3]);
  *(short4v*)&xb[idx] = o;
}

// w [512][N] fp32 -> wT [N][512] bf16 (transposed), 32x32 LDS tiles
__global__ __launch_bounds__(256) void cast_w_T(
    const float* __restrict__ w, short* __restrict__ wT, int N)
{
  __shared__ float t[32][33];
  const int k0 = blockIdx.x * 32;
  const int n0 = blockIdx.y * 32;
  const int c = threadIdx.x & 31, r = threadIdx.x >> 5;  // r: 0..7
#pragma unroll
  for (int p = 0; p < 4; ++p)
    t[r + p * 8][c] = w[(size_t)(k0 + r + p * 8) * N + n0 + c];
  __syncthreads();
#pragma unroll
  for (int p = 0; p < 4; ++p)
    wT[(size_t)(n0 + r + p * 8) * 512 + k0 + c] = f2bf(t[c][r + p * 8]);
}

// Wc[k][c] = sum_m w_qkv[k][m] * w_od[m][c]  (m < 512, Q columns)
// bc[c] = sum_m b_qkv[m] * w_od[m][c] + b_od[c]
__global__ __launch_bounds__(256) void w_comb(
    const float* __restrict__ w_qkv, const float* __restrict__ b_qkv,
    const float* __restrict__ w_od, const float* __restrict__ b_od,
    float* __restrict__ Wc, float* __restrict__ bc)
{
  __shared__ float Lod[512 * 16];
  __shared__ float pb[16][17];
  const int tid = threadIdx.x;
#pragma unroll
  for (int p = 0; p < 8; ++p) {
    int idx = (p * 256 + tid) * 4;
    *(vf4*)&Lod[idx] = *(const vf4*)&w_od[idx];
  }
  __syncthreads();

  if (blockIdx.x < 32) {
    const int k = blockIdx.x * 16 + (tid >> 4);
    const int c = tid & 15;
    float s = 0.0f;
    for (int m = 0; m < E; m += 4) {
      vf4 wq = *(const vf4*)&w_qkv[(size_t)k * 1536 + m];
      s += wq[0] * Lod[(m + 0) * 16 + c] + wq[1] * Lod[(m + 1) * 16 + c]
         + wq[2] * Lod[(m + 2) * 16 + c] + wq[3] * Lod[(m + 3) * 16 + c];
    }
    Wc[k * 16 + c] = s;
  } else {
    const int c = tid & 15, seg = tid >> 4;
    float s = 0.0f;
    for (int m = seg * 32; m < seg * 32 + 32; ++m)
      s += b_qkv[m] * Lod[m * 16 + c];
    pb[seg][c] = s;
    __syncthreads();
    if (tid < 16) {
      float acc = b_od[tid];
#pragma unroll
      for (int g = 0; g < 16; ++g) acc += pb[g][tid];
      bc[tid] = acc;
    }
  }
}

// =====================================================================
// qkv GEMM (bf16 MFMA): qkvb[4096][1536] = xb @ w_qkv (+bias),
// Q columns (<512) pre-scaled by SCALE. Tile 128x128, BK=32, 4 waves 2x2.
// =====================================================================
__global__ __launch_bounds__(256) void qkv_gemm_bf16(
    const short* __restrict__ xb, const short* __restrict__ wT,
    const float* __restrict__ bias, short* __restrict__ qkvb)
{
  __shared__ __align__(16) short As[128 * 40];
  __shared__ __align__(16) short Bt[128 * 40];

  const int tid = threadIdx.x;
  const int wave = tid >> 6, lane = tid & 63;
  const int quad = lane >> 4, l15 = lane & 15;
  const int wm = wave >> 1, wn = wave & 1;
  const int m0 = blockIdx.y * 128, n0 = blockIdx.x * 128;

  f32x4 acc[4][4];
#pragma unroll
  for (int mi = 0; mi < 4; ++mi)
#pragma unroll
    for (int ni = 0; ni < 4; ++ni) acc[mi][ni] = (f32x4){0, 0, 0, 0};

  const int sr = tid >> 1, sc = (tid & 1) * 16;

#pragma unroll 1
  for (int k0 = 0; k0 < E; k0 += 32) {
    __syncthreads();
    *(bf16x8*)&As[sr * 40 + sc] =
        *(const bf16x8*)&xb[(size_t)(m0 + sr) * 512 + k0 + sc];
    *(bf16x8*)&As[sr * 40 + sc + 8] =
        *(const bf16x8*)&xb[(size_t)(m0 + sr) * 512 + k0 + sc + 8];
    *(bf16x8*)&Bt[sr * 40 + sc] =
        *(const bf16x8*)&wT[(size_t)(n0 + sr) * 512 + k0 + sc];
    *(bf16x8*)&Bt[sr * 40 + sc + 8] =
        *(const bf16x8*)&wT[(size_t)(n0 + sr) * 512 + k0 + sc + 8];
    __syncthreads();

    bf16x8 aA[4], bB[4];
#pragma unroll
    for (int mi = 0; mi < 4; ++mi)
      aA[mi] = *(const bf16x8*)&As[(wm * 64 + mi * 16 + l15) * 40 + quad * 8];
#pragma unroll
    for (int ni = 0; ni < 4; ++ni)
      bB[ni] = *(const bf16x8*)&Bt[(wn * 64 + ni * 16 + l15) * 40 + quad * 8];
#pragma unroll
    for (int mi = 0; mi < 4; ++mi)
#pragma unroll
      for (int ni = 0; ni < 4; ++ni)
        acc[mi][ni] = __builtin_amdgcn_mfma_f32_16x16x32_bf16(
            aA[mi], bB[ni], acc[mi][ni], 0, 0, 0);
  }

#pragma unroll
  for (int mi = 0; mi < 4; ++mi)
#pragma unroll
    for (int ni = 0; ni < 4; ++ni)
#pragma unroll
      for (int r = 0; r < 4; ++r) {
        int row = m0 + wm * 64 + mi * 16 + quad * 4 + r;
        int col = n0 + wn * 64 + ni * 16 + l15;
        float v = acc[mi][ni][r] + bias[col];
        if (col < 512) v *= SCALE;
        qkvb[(size_t)row * 1536 + col] = f2bf(v);
      }
}

// =====================================================================
// od (fp32 exact) + window params.
// prm: 7 arrays of [NT]: bl, br, w_bl, w_br, anchor_l, a_frac, rowscale
// Fully-masked rows rewritten to window [0,T-1], rowscale=0 (handled in
// flash by zeroing the Q fragment -> uniform softmax, matching ref).
// =====================================================================
__global__ __launch_bounds__(256) void od_params(
    const float* __restrict__ x, const float* __restrict__ Wc,
    const float* __restrict__ bc, float* __restrict__ prm)
{
  __shared__ float od_s[16][16];
  const int tid = threadIdx.x;
  const int r = tid >> 4, c = tid & 15;
  const int row = blockIdx.x * 16 + r;

  float sum = bc[c];
  const float* qr = x + (size_t)row * E;
  for (int k = 0; k < E; k += 4) {
    vf4 q = *(const vf4*)&qr[k];
    sum += q[0] * Wc[(k + 0) * 16 + c]
         + q[1] * Wc[(k + 1) * 16 + c]
         + q[2] * Wc[(k + 2) * 16 + c]
         + q[3] * Wc[(k + 3) * 16 + c];
  }
  od_s[r][c] = sum;
  __syncthreads();

  if (tid < 128) {
    const int rr = tid >> 3, h = tid & 7;
    const int grow = blockIdx.x * 16 + rr;
    const int b = grow / T, i = grow % T;
    float o = od_s[rr][h];
    float d = od_s[rr][h + 8];
    float offset   = tanhf(o) * (float)T;
    float duration = (float)T / (1.0f + expf(-d));
    float anchor = (float)i + offset;
    float start = anchor - duration;
    float end   = anchor + duration;
    float bl = floorf(start);
    float br = ceilf(end);
    float al = floorf(anchor);
    float wbl = bl - start;
    float wbr = end - br;
    float af  = anchor - al;
    float rsc = 1.0f;
    if (br < 0.0f || bl > (float)(T - 1)) {
      bl = 0.0f; br = (float)(T - 1);
      wbl = 0.0f; wbr = 0.0f; al = -5.0f; af = 0.0f;
      rsc = 0.0f;
    }
    int idx = (b * NH + h) * T + i;
    prm[0 * NT + idx] = bl;
    prm[1 * NT + idx] = br;
    prm[2 * NT + idx] = wbl;
    prm[3 * NT + idx] = wbr;
    prm[4 * NT + idx] = al;
    prm[5 * NT + idx] = af;
    prm[6 * NT + idx] = rsc;
  }
}

// =====================================================================
// V pre-transpose: Vtg[bh][hd][t] (bf16) from qkvb V-section.
// =====================================================================
__global__ __launch_bounds__(256) void v_transpose(
    const short* __restrict__ qkvb, short* __restrict__ Vtg)
{
  __shared__ __align__(16) short Tt[64 * 72];
  const int tid = threadIdx.x;
  const int t0 = blockIdx.x * 64, bh = blockIdx.y;
  const int b = bh >> 3, h = bh & 7;
  const int rq = tid >> 3, cb = (tid & 7) * 8;
#pragma unroll
  for (int it = 0; it < 2; ++it) {
    int rr = it * 32 + rq;   // t-local
    bf16x8 v = *(const bf16x8*)&qkvb[(size_t)(b * T + t0 + rr) * 1536 + 1024 + h * 64 + cb];
#pragma unroll
    for (int j = 0; j < 8; ++j) Tt[(cb + j) * 72 + rr] = v[j];
  }
  __syncthreads();
  const int hd = tid >> 2, tc = (tid & 3) * 16;
  *(bf16x8*)&Vtg[(size_t)(bh * 64 + hd) * T + t0 + tc] =
      *(const bf16x8*)&Tt[hd * 72 + tc];
  *(bf16x8*)&Vtg[(size_t)(bh * 64 + hd) * T + t0 + tc + 8] =
      *(const bf16x8*)&Tt[hd * 72 + tc + 8];
}

// =====================================================================
// MFMA flash attention, transposed-S formulation.
// S^T = mfma(K_frag, Q_frag): lane = query row i, regs = key j.
// Row params are per-lane scalars; P emerges j-contiguous per lane ->
// packed b64 LDS writes, b128 reads, NO barrier (wave-private);
// PV = mfma(V^T_frag, P_frag) -> O^T; l is a per-lane scalar sum.
// Grid (T/64, BH, 2) K-split; fixed-max softmax (scores bounded),
// masked -> -80 -> exp ~ 0; degenerate rows via zeroed Q fragment.
// =====================================================================
__global__ __launch_bounds__(256, 4) void flash_attn_mfma3(
    const short* __restrict__ qkvb, const short* __restrict__ Vtg,
    const float* __restrict__ prm,
    float* __restrict__ Opart, float* __restrict__ lpart)
{
  __shared__ __align__(16) short Ks[64 * 72];
  __shared__ __align__(16) short Vt[64 * 72];
  __shared__ __align__(16) short Ps[4][16 * 72];
  __shared__ float u_s[8];

  const int tid = threadIdx.x;
  const int wave = tid >> 6, lane = tid & 63;
  const int quad = lane >> 4, l15 = lane & 15;
  const int qt = blockIdx.x, bh = blockIdx.y, ks = blockIdx.z;
  const int b = bh >> 3, h = bh & 7;
  const int i0 = qt * 64;
  const int i = i0 + wave * 16 + l15;          // this lane's query row

  // per-lane row params (scalars)
  const int pidx = bh * T + i;
  float blf = prm[0 * NT + pidx];
  float brf = prm[1 * NT + pidx];
  float wbl = prm[2 * NT + pidx];
  float wbr = prm[3 * NT + pidx];
  float alf = prm[4 * NT + pidx];
  float afr = prm[5 * NT + pidx];
  float rsc = prm[6 * NT + pidx];
  const int bli = (int)blf, widi = (int)brf - bli, ali = (int)alf;
  const unsigned widu = (unsigned)widi;
  const float a1 = 1.0f - afr;

  // Q fragment in registers (B-frag pattern: lane = i, regs = hd)
  bf16x8 aQ0, aQ1;
  {
    size_t bq = (size_t)(b * T + i) * 1536 + h * 64;
    aQ0 = *(const bf16x8*)&qkvb[bq + quad * 8];
    aQ1 = *(const bf16x8*)&qkvb[bq + 32 + quad * 8];
    if (rsc == 0.0f) {
      bf16x8 z = {0, 0, 0, 0, 0, 0, 0, 0};
      aQ0 = z; aQ1 = z;
    }
  }

  // block union of windows -> K-tile range for this half
  float bmn = blf, bmx = brf;
#pragma unroll
  for (int d = 1; d < 64; d <<= 1) {
    bmn = fminf(bmn, __shfl_xor(bmn, d));
    bmx = fmaxf(bmx, __shfl_xor(bmx, d));
  }
  if (lane == 0) { u_s[wave * 2] = bmn; u_s[wave * 2 + 1] = bmx; }
  __syncthreads();
  bmn = fminf(fminf(u_s[0], u_s[2]), fminf(u_s[4], u_s[6]));
  bmx = fmaxf(fmaxf(u_s[1], u_s[3]), fmaxf(u_s[5], u_s[7]));
  const int ktlo = max(ks * 16, max(((int)bmn) >> 6, 0));
  const int kthi = min(ks * 16 + 15, min(((int)bmx) >> 6, T / 64 - 1));

  f32x4 o[4];
#pragma unroll
  for (int c = 0; c < 4; ++c) o[c] = (f32x4){0, 0, 0, 0};
  float lacc = 0.0f;

  const int rq = tid >> 3, cb = (tid & 7) * 8;

#pragma unroll 1
  for (int kt = ktlo; kt <= kthi; ++kt) {
    const int j0 = kt * 64;
    __syncthreads();   // prior-iter Ks/Vt reads done
#pragma unroll
    for (int it = 0; it < 2; ++it) {
      int rr = it * 32 + rq;
      *(bf16x8*)&Ks[rr * 72 + cb] =
          *(const bf16x8*)&qkvb[(size_t)(b * T + j0 + rr) * 1536 + 512 + h * 64 + cb];
      *(bf16x8*)&Vt[rr * 72 + cb] =
          *(const bf16x8*)&Vtg[(size_t)(bh * 64 + rr) * T + j0 + cb];
    }
    __syncthreads();

    // ---- S^T = K Q^T: regs = j (quad*4+r per 16-block), lane = i ----
    f32x4 s[4];
#pragma unroll
    for (int nc = 0; nc < 4; ++nc) {
      const short* kb = &Ks[(nc * 16 + l15) * 72 + quad * 8];
      f32x4 a = (f32x4){0, 0, 0, 0};
      a = __builtin_amdgcn_mfma_f32_16x16x32_bf16(*(const bf16x8*)&kb[0],  aQ0, a, 0, 0, 0);
      a = __builtin_amdgcn_mfma_f32_16x16x32_bf16(*(const bf16x8*)&kb[32], aQ1, a, 0, 0, 0);
      s[nc] = a;
    }

    // ---- weights + mask + exp; P row-major into wave-private LDS ----
    const int dq  = j0 + quad * 4 - bli;
    const int dq2 = j0 + quad * 4 - ali;
#pragma unroll
    for (int nc = 0; nc < 4; ++nc) {
      const int dn = dq + nc * 16, d2n = dq2 + nc * 16;
      float pr[4];
#pragma unroll
      for (int r = 0; r < 4; ++r) {
        int d = dn + r, d2 = d2n + r;
        float e  = (d == 0) ? wbl : ((d == widi) ? wbr : 0.0f);
        float aw = (d2 == 0) ? a1 : ((d2 == 1) ? afr : 0.0f);
        float w = 1.0f + e + aw;
        float v = s[nc][r] * w;                    // SCALE already in Q
        v = ((unsigned)d <= widu) ? v : -80.0f;
        float p = __expf(v);
        lacc += p;
        pr[r] = p;
      }
      int2v pk;
      pk[0] = (int)pk2bf(pr[0], pr[1]);
      pk[1] = (int)pk2bf(pr[2], pr[3]);
      *(int2v*)&Ps[wave][l15 * 72 + nc * 16 + quad * 4] = pk;
    }
    // wave-private: no barrier needed (lgkmcnt ordering within wave)

    // ---- O^T += V^T P^T ----
    bf16x8 bP0 = *(const bf16x8*)&Ps[wave][l15 * 72 + quad * 8];
    bf16x8 bP1 = *(const bf16x8*)&Ps[wave][l15 * 72 + 32 + quad * 8];
#pragma unroll
    for (int nc2 = 0; nc2 < 4; ++nc2) {
      const short* vb = &Vt[(nc2 * 16 + l15) * 72 + quad * 8];
      o[nc2] = __builtin_amdgcn_mfma_f32_16x16x32_bf16(
          *(const bf16x8*)&vb[0],  bP0, o[nc2], 0, 0, 0);
      o[nc2] = __builtin_amdgcn_mfma_f32_16x16x32_bf16(
          *(const bf16x8*)&vb[32], bP1, o[nc2], 0, 0, 0);
    }
  }

  // l: sum the 4 quads holding the same row i
  lacc += __shfl_xor(lacc, 16);
  lacc += __shfl_xor(lacc, 32);
  if (lane < 16)
    lpart[ks * NT + bh * T + i] = lacc;

  // O^T epilogue: lane = row i, regs = channels c
  size_t ob = (size_t)ks * (B * T * E) + (size_t)(b * T + i) * E + h * 64;
#pragma unroll
  for (int nc2 = 0; nc2 < 4; ++nc2)
    *(f32x4*)&Opart[ob + nc2 * 16 + quad * 4] = o[nc2];
}

// =====================================================================
// attn = (O0 + O1) / (l0 + l1), cast bf16
// =====================================================================
__global__ __launch_bounds__(256) void combine_attn(
    const float* __restrict__ Opart, const float* __restrict__ lpart,
    short* __restrict__ attnb)
{
  int base = (blockIdx.x * 256 + threadIdx.x) * 4;
  int row = base >> 9;            // / 512
  int c = base & 511;
  int h = c >> 6;
  int b = row >> 11;              // / T
  int i = row & (T - 1);
  int lidx = ((b << 3) + h) * T + i;
  float l = lpart[lidx] + lpart[NT + lidx];
  float inv = 1.0f / l;
  vf4 o0 = *(const vf4*)&Opart[base];
  vf4 o1 = *(const vf4*)&Opart[(size_t)(B * T * E) + base];
  short4v ov;
#pragma unroll
  for (int j = 0; j < 4; ++j) ov[j] = f2bf((o0[j] + o1[j]) * inv);
  *(short4v*)&attnb[base] = ov;
}

// =====================================================================
// out GEMM (bf16 MFMA): out[4096][512] = attnb @ w_out + b_out (fp32 out)
// Tile 64x64, BK=32, 4 waves (2x2, each 32x32). Grid (8, 64).
// =====================================================================
__global__ __launch_bounds__(256) void out_gemm_bf16(
    const short* __restrict__ Ab, const short* __restrict__ wT,
    const float* __restrict__ bias, float* __restrict__ Co)
{
  __shared__ __align__(16) short As[64 * 40];
  __shared__ __align__(16) short Bt[64 * 40];

  const int tid = threadIdx.x;
  const int wave = tid >> 6, lane = tid & 63;
  const int quad = lane >> 4, l15 = lane & 15;
  const int wm = wave >> 1, wn = wave & 1;
  const int m0 = blockIdx.y * 64, n0 = blockIdx.x * 64;

  f32x4 acc[2][2];
#pragma unroll
  for (int mi = 0; mi < 2; ++mi)
#pragma unroll
    for (int ni = 0; ni < 2; ++ni) acc[mi][ni] = (f32x4){0, 0, 0, 0};

  const int ar = tid >> 2, akc = (tid & 3) * 8;

#pragma unroll 1
  for (int k0 = 0; k0 < E; k0 += 32) {
    __syncthreads();
    *(bf16x8*)&As[ar * 40 + akc] =
        *(const bf16x8*)&Ab[(size_t)(m0 + ar) * 512 + k0 + akc];
    *(bf16x8*)&Bt[ar * 40 + akc] =
        *(const bf16x8*)&wT[(size_t)(n0 + ar) * 512 + k0 + akc];
    __syncthreads();

    bf16x8 aA[2], bB[2];
#pragma unroll
    for (int mi = 0; mi < 2; ++mi)
      aA[mi] = *(const bf16x8*)&As[(wm * 32 + mi * 16 + l15) * 40 + quad * 8];
#pragma unroll
    for (int ni = 0; ni < 2; ++ni)
      bB[ni] = *(const bf16x8*)&Bt[(wn * 32 + ni * 16 + l15) * 40 + quad * 8];
#pragma unroll
    for (int mi = 0; mi < 2; ++mi)
#pragma unroll
      for (int ni = 0; ni < 2; ++ni)
        acc[mi][ni] = __builtin_amdgcn_mfma_f32_16x16x32_bf16(
            aA[mi], bB[ni], acc[mi][ni], 0, 0, 0);
  }

#pragma unroll
  for (int mi = 0; mi < 2; ++mi)
#pragma unroll
    for (int ni = 0; ni < 2; ++ni)
#pragma unroll
      for (int r = 0; r < 4; ++r) {
        int row = m0 + wm * 32 + mi * 16 + quad * 4 + r;
        int col = n0 + wn * 32 + ni * 16 + l15;
        Co[(size_t)row * 512 + col] = acc[mi][ni][r] + bias[col];
      }
}

// =====================================================================
extern "C" void kernel_launch(void* const* d_in, const int* in_sizes, int n_in,
                              void* d_out, int out_size, void* d_ws, size_t ws_size,
                              hipStream_t stream)
{
  const float* x     = (const float*)d_in[0];
  const float* w_qkv = (const float*)d_in[1];
  const float* b_qkv = (const float*)d_in[2];
  const float* w_od  = (const float*)d_in[3];
  const float* b_od  = (const float*)d_in[4];
  const float* w_out = (const float*)d_in[5];
  const float* b_out = (const float*)d_in[6];
  float* out = (float*)d_out;

  char* w = (char*)d_ws;
  short* xb    = (short*)w;  w += (size_t)B * T * E * 2;          // 4 MB
  short* wTq   = (short*)w;  w += (size_t)E * 3 * E * 2;          // 1.5 MB
  short* wTo   = (short*)w;  w += (size_t)E * E * 2;              // 0.5 MB
  short* qkvb  = (short*)w;  w += (size_t)B * T * 3 * E * 2;      // 12.6 MB
  float* Wc    = (float*)w;  w += (size_t)E * 16 * 4;             // 32 KB
  float* bc    = (float*)w;  w += 256;
  float* prm   = (float*)w;  w += (size_t)7 * NT * 4;             // 896 KB
  float* Opart = (float*)w;  w += (size_t)2 * B * T * E * 4;      // 16.8 MB
  float* lpart = (float*)w;  w += (size_t)2 * NT * 4;             // 256 KB
  short* attnb = (short*)w;  w += (size_t)B * T * E * 2;          // 4 MB
  short* Vtg   = xb;   // alias: xb dead after qkv_gemm; same size (4 MB)

  // 1) casts + combined od weights
  cast_x_bf16<<<dim3(B * T * E / 1024), 256, 0, stream>>>(x, xb);
  cast_w_T<<<dim3(E / 32, 3 * E / 32), 256, 0, stream>>>(w_qkv, wTq, 3 * E);
  cast_w_T<<<dim3(E / 32, E / 32), 256, 0, stream>>>(w_out, wTo, E);
  w_comb<<<dim3(33), 256, 0, stream>>>(w_qkv, b_qkv, w_od, b_od, Wc, bc);

  // 2) qkv = x @ w_qkv + b_qkv  (bf16 MFMA, Q pre-scaled)
  qkv_gemm_bf16<<<dim3(3 * E / 128, B * T / 128), 256, 0, stream>>>(
      xb, wTq, b_qkv, qkvb);

  // 3) window params (fp32 exact)
  od_params<<<dim3(B * T / 16), 256, 0, stream>>>(x, Wc, bc, prm);

  // 4) V pre-transpose (overwrites xb — safe, xb consumed by qkv_gemm)
  v_transpose<<<dim3(T / 64, BH), 256, 0, stream>>>(qkvb, Vtg);

  // 5) attention (transposed-S MFMA flash, K-split 2-way)
  flash_attn_mfma3<<<dim3(T / 64, BH, 2), 256, 0, stream>>>(
      qkvb, Vtg, prm, Opart, lpart);

  // 6) combine partials -> attn bf16
  combine_attn<<<dim3(B * T * E / 1024), 256, 0, stream>>>(Opart, lpart, attnb);

  // 7) out = attn @ w_out + b_out (bf16 MFMA, fp32 out)
  out_gemm_bf16<<<dim3(E / 64, B * T / 64), 256, 0, stream>>>(
      attnb, wTo, b_out, out);
}

// Round 6
// 183.219 us; speedup vs baseline: 1.0797x; 1.0797x over previous
//
#include <hip/hip_runtime.h>
#include <math.h>

typedef float vf4 __attribute__((ext_vector_type(4)));
typedef float f32x4 __attribute__((ext_vector_type(4)));
typedef short bf16x8 __attribute__((ext_vector_type(8)));
typedef short short4v __attribute__((ext_vector_type(4)));
typedef int int2v __attribute__((ext_vector_type(2)));
typedef int int4v __attribute__((ext_vector_type(4)));

constexpr int B = 2, T = 2048, E = 512, NH = 8, HD = 64;
constexpr int BH = B * NH;            // 16
constexpr int NT = BH * T;            // 32768
constexpr float SCALE = 0.125f;       // HD^-0.5
constexpr float LOG2E = 1.44269504088896f;
constexpr float QSC = SCALE * LOG2E;  // folded into Q -> S in log2 domain

static __device__ __forceinline__ short f2bf(float f) {
  unsigned u = __float_as_uint(f);
  unsigned r = (u + 0x7fffu + ((u >> 16) & 1u)) >> 16;   // RNE
  return (short)r;
}
static __device__ __forceinline__ unsigned pk2bf(float a, float b) {  // RNE pack
  unsigned lo = (unsigned)(unsigned short)f2bf(a);
  unsigned hi = (unsigned)(unsigned short)f2bf(b);
  return lo | (hi << 16);
}
// cheap half-up bf16 pack (unbiased, <=2^-9 rel err) — inner-loop use
static __device__ __forceinline__ unsigned pkhu(float a, float b) {
  unsigned ua = __float_as_uint(a) + 0x8000u;
  unsigned ub = __float_as_uint(b) + 0x8000u;
  return __builtin_amdgcn_perm(ub, ua, 0x07060302u);  // [ua.hi16 | ub.hi16]
}
#if __has_builtin(__builtin_amdgcn_exp2f)
#define EXP2F(x) __builtin_amdgcn_exp2f(x)
#else
#define EXP2F(x) exp2f(x)
#endif
static __device__ __forceinline__ float bf2f(short s) {
  return __uint_as_float(((unsigned)(unsigned short)s) << 16);
}

// =====================================================================
// prep_all: fused cast_x | w_qkv^T | w_out^T | w_comb.  Grid 3105 blocks.
// =====================================================================
__global__ __launch_bounds__(256) void prep_all(
    const float* __restrict__ x, const float* __restrict__ w_qkv,
    const float* __restrict__ b_qkv, const float* __restrict__ w_od,
    const float* __restrict__ b_od,
    short* __restrict__ xb, short* __restrict__ wTq, short* __restrict__ wTo,
    const float* __restrict__ w_out, float* __restrict__ Wc,
    float* __restrict__ bc)
{
  __shared__ float sh[8464];
  const int bid = blockIdx.x;
  const int tid = threadIdx.x;

  if (bid < 2048) {                       // ---- cast x -> bf16
    int idx = (bid * 256 + tid) * 4;
    vf4 v = *(const vf4*)&x[idx];
    short4v o;
    o[0] = f2bf(v[0]); o[1] = f2bf(v[1]); o[2] = f2bf(v[2]); o[3] = f2bf(v[3]);
    *(short4v*)&xb[idx] = o;
  } else if (bid < 3072) {                // ---- transpose-cast weights
    const float* w; short* wT; int N, t;
    if (bid < 2816) { t = bid - 2048; w = w_qkv; wT = wTq; N = 1536; }
    else            { t = bid - 2816; w = w_out; wT = wTo; N = 512; }
    float (*tt)[33] = (float(*)[33])sh;
    const int k0 = (t & 15) * 32;
    const int n0 = (t >> 4) * 32;
    const int c = tid & 31, r = tid >> 5;  // r: 0..7
#pragma unroll
    for (int p = 0; p < 4; ++p)
      tt[r + p * 8][c] = w[(size_t)(k0 + r + p * 8) * N + n0 + c];
    __syncthreads();
#pragma unroll
    for (int p = 0; p < 4; ++p)
      wT[(size_t)(n0 + r + p * 8) * 512 + k0 + c] = f2bf(tt[c][r + p * 8]);
  } else {                                // ---- w_comb
    float* Lod = sh;                 // 512*16
    float (*pb)[17] = (float(*)[17])(sh + 8192);
    const int bx = bid - 3072;       // 0..32
#pragma unroll
    for (int p = 0; p < 8; ++p) {
      int idx = (p * 256 + tid) * 4;
      *(vf4*)&Lod[idx] = *(const vf4*)&w_od[idx];
    }
    __syncthreads();
    if (bx < 32) {
      const int k = bx * 16 + (tid >> 4);
      const int c = tid & 15;
      float s = 0.0f;
      for (int m = 0; m < E; m += 4) {
        vf4 wq = *(const vf4*)&w_qkv[(size_t)k * 1536 + m];
        s += wq[0] * Lod[(m + 0) * 16 + c] + wq[1] * Lod[(m + 1) * 16 + c]
           + wq[2] * Lod[(m + 2) * 16 + c] + wq[3] * Lod[(m + 3) * 16 + c];
      }
      Wc[k * 16 + c] = s;
    } else {
      const int c = tid & 15, seg = tid >> 4;
      float s = 0.0f;
      for (int m = seg * 32; m < seg * 32 + 32; ++m)
        s += b_qkv[m] * Lod[m * 16 + c];
      pb[seg][c] = s;
      __syncthreads();
      if (tid < 16) {
        float acc = b_od[tid];
#pragma unroll
        for (int g = 0; g < 16; ++g) acc += pb[g][tid];
        bc[tid] = acc;
      }
    }
  }
}

// =====================================================================
// qkv GEMM (bf16 MFMA): Q cols pre-scaled by SCALE*LOG2E -> qkvb;
// K cols -> qkvb; V cols written TRANSPOSED to Vtg[bh*64+hd][t].
// Tile 128x128, BK=32, 4 waves 2x2.
// =====================================================================
__global__ __launch_bounds__(256) void qkv_gemm_bf16(
    const short* __restrict__ xb, const short* __restrict__ wT,
    const float* __restrict__ bias, short* __restrict__ qkvb,
    short* __restrict__ Vtg)
{
  __shared__ __align__(16) short As[128 * 40];
  __shared__ __align__(16) short Bt[128 * 40];

  const int tid = threadIdx.x;
  const int wave = tid >> 6, lane = tid & 63;
  const int quad = lane >> 4, l15 = lane & 15;
  const int wm = wave >> 1, wn = wave & 1;
  const int m0 = blockIdx.y * 128, n0 = blockIdx.x * 128;

  f32x4 acc[4][4];
#pragma unroll
  for (int mi = 0; mi < 4; ++mi)
#pragma unroll
    for (int ni = 0; ni < 4; ++ni) acc[mi][ni] = (f32x4){0, 0, 0, 0};

  const int sr = tid >> 1, sc = (tid & 1) * 16;

#pragma unroll 1
  for (int k0 = 0; k0 < E; k0 += 32) {
    __syncthreads();
    *(bf16x8*)&As[sr * 40 + sc] =
        *(const bf16x8*)&xb[(size_t)(m0 + sr) * 512 + k0 + sc];
    *(bf16x8*)&As[sr * 40 + sc + 8] =
        *(const bf16x8*)&xb[(size_t)(m0 + sr) * 512 + k0 + sc + 8];
    *(bf16x8*)&Bt[sr * 40 + sc] =
        *(const bf16x8*)&wT[(size_t)(n0 + sr) * 512 + k0 + sc];
    *(bf16x8*)&Bt[sr * 40 + sc + 8] =
        *(const bf16x8*)&wT[(size_t)(n0 + sr) * 512 + k0 + sc + 8];
    __syncthreads();

    bf16x8 aA[4], bB[4];
#pragma unroll
    for (int mi = 0; mi < 4; ++mi)
      aA[mi] = *(const bf16x8*)&As[(wm * 64 + mi * 16 + l15) * 40 + quad * 8];
#pragma unroll
    for (int ni = 0; ni < 4; ++ni)
      bB[ni] = *(const bf16x8*)&Bt[(wn * 64 + ni * 16 + l15) * 40 + quad * 8];
#pragma unroll
    for (int mi = 0; mi < 4; ++mi)
#pragma unroll
      for (int ni = 0; ni < 4; ++ni)
        acc[mi][ni] = __builtin_amdgcn_mfma_f32_16x16x32_bf16(
            aA[mi], bB[ni], acc[mi][ni], 0, 0, 0);
  }

#pragma unroll
  for (int mi = 0; mi < 4; ++mi)
#pragma unroll
    for (int ni = 0; ni < 4; ++ni) {
      const int col = n0 + wn * 64 + ni * 16 + l15;     // uniform branch per ni
      const int rowb = m0 + wm * 64 + mi * 16 + quad * 4;
      const float bs = bias[col];
      if (col < 1024) {
        const float qs = (col < 512) ? QSC : 1.0f;
#pragma unroll
        for (int r = 0; r < 4; ++r)
          qkvb[(size_t)(rowb + r) * 1536 + col] = f2bf((acc[mi][ni][r] + bs) * qs);
      } else {
        // V: transposed write  Vtg[(b*8+h)*64+hd][t]
        const int h = (col - 1024) >> 6, hd = col & 63;
        const int b = rowb >> 11, tt = rowb & 2047;
        int2v pk;
        pk[0] = (int)pk2bf(acc[mi][ni][0] + bs, acc[mi][ni][1] + bs);
        pk[1] = (int)pk2bf(acc[mi][ni][2] + bs, acc[mi][ni][3] + bs);
        *(int2v*)&Vtg[(size_t)(((b << 3) + h) * 64 + hd) * T + tt] = pk;
      }
    }
}

// =====================================================================
// od (fp32 exact) + window params.
// prm: 7 arrays of [NT]: bl, br, w_bl, w_br, anchor_l, a_frac, rowscale
// =====================================================================
__global__ __launch_bounds__(256) void od_params(
    const float* __restrict__ x, const float* __restrict__ Wc,
    const float* __restrict__ bc, float* __restrict__ prm)
{
  __shared__ float od_s[16][16];
  const int tid = threadIdx.x;
  const int r = tid >> 4, c = tid & 15;
  const int row = blockIdx.x * 16 + r;

  float sum = bc[c];
  const float* qr = x + (size_t)row * E;
  for (int k = 0; k < E; k += 4) {
    vf4 q = *(const vf4*)&qr[k];
    sum += q[0] * Wc[(k + 0) * 16 + c]
         + q[1] * Wc[(k + 1) * 16 + c]
         + q[2] * Wc[(k + 2) * 16 + c]
         + q[3] * Wc[(k + 3) * 16 + c];
  }
  od_s[r][c] = sum;
  __syncthreads();

  if (tid < 128) {
    const int rr = tid >> 3, h = tid & 7;
    const int grow = blockIdx.x * 16 + rr;
    const int b = grow / T, i = grow % T;
    float o = od_s[rr][h];
    float d = od_s[rr][h + 8];
    float offset   = tanhf(o) * (float)T;
    float duration = (float)T / (1.0f + expf(-d));
    float anchor = (float)i + offset;
    float start = anchor - duration;
    float end   = anchor + duration;
    float bl = floorf(start);
    float br = ceilf(end);
    float al = floorf(anchor);
    float wbl = bl - start;
    float wbr = end - br;
    float af  = anchor - al;
    float rsc = 1.0f;
    if (br < 0.0f || bl > (float)(T - 1)) {
      bl = 0.0f; br = (float)(T - 1);
      wbl = 0.0f; wbr = 0.0f; al = -5.0f; af = 0.0f;
      rsc = 0.0f;
    }
    int idx = (b * NH + h) * T + i;
    prm[0 * NT + idx] = bl;
    prm[1 * NT + idx] = br;
    prm[2 * NT + idx] = wbl;
    prm[3 * NT + idx] = wbr;
    prm[4 * NT + idx] = al;
    prm[5 * NT + idx] = af;
    prm[6 * NT + idx] = rsc;
  }
}

// =====================================================================
// MFMA flash attention, transposed-S, log2-domain scores, K-split 2-way.
// Per-tile wave-uniform fast path: interior tiles (inside every row's
// window, no special positions) do p = exp2(s) only. Slow path handles
// edges/anchor/mask. Opart in bf16.
// =====================================================================
__global__ __launch_bounds__(256, 4) void flash_attn_mfma4(
    const short* __restrict__ qkvb, const short* __restrict__ Vtg,
    const float* __restrict__ prm,
    short* __restrict__ Opart, float* __restrict__ lpart)
{
  __shared__ __align__(16) short Ks[64 * 72];
  __shared__ __align__(16) short Vt[64 * 72];
  __shared__ __align__(16) short Ps[4][16 * 72];
  __shared__ float u_s[8];

  const int tid = threadIdx.x;
  const int wave = tid >> 6, lane = tid & 63;
  const int quad = lane >> 4, l15 = lane & 15;
  const int qt = blockIdx.x, bh = blockIdx.y, ks = blockIdx.z;
  const int b = bh >> 3, h = bh & 7;
  const int i0 = qt * 64;
  const int i = i0 + wave * 16 + l15;          // this lane's query row

  const int pidx = bh * T + i;
  float blf = prm[0 * NT + pidx];
  float brf = prm[1 * NT + pidx];
  float wbl = prm[2 * NT + pidx];
  float wbr = prm[3 * NT + pidx];
  float alf = prm[4 * NT + pidx];
  float afr = prm[5 * NT + pidx];
  float rsc = prm[6 * NT + pidx];
  const int bli = (int)blf, widi = (int)brf - bli, ali = (int)alf;
  const unsigned widu = (unsigned)widi;
  const float a1 = 1.0f - afr;

  // Q fragment (B-frag: lane = i, regs = hd); zeroed for degenerate rows
  bf16x8 aQ0, aQ1;
  {
    size_t bq = (size_t)(b * T + i) * 1536 + h * 64;
    aQ0 = *(const bf16x8*)&qkvb[bq + quad * 8];
    aQ1 = *(const bf16x8*)&qkvb[bq + 32 + quad * 8];
    if (rsc == 0.0f) {
      bf16x8 z = {0, 0, 0, 0, 0, 0, 0, 0};
      aQ0 = z; aQ1 = z;
    }
  }

  // block union of windows -> K-tile range for this half
  float bmn = blf, bmx = brf;
#pragma unroll
  for (int d = 1; d < 64; d <<= 1) {
    bmn = fminf(bmn, __shfl_xor(bmn, d));
    bmx = fmaxf(bmx, __shfl_xor(bmx, d));
  }
  if (lane == 0) { u_s[wave * 2] = bmn; u_s[wave * 2 + 1] = bmx; }
  __syncthreads();
  bmn = fminf(fminf(u_s[0], u_s[2]), fminf(u_s[4], u_s[6]));
  bmx = fmaxf(fmaxf(u_s[1], u_s[3]), fmaxf(u_s[5], u_s[7]));
  const int ktlo = max(ks * 16, max(((int)bmn) >> 6, 0));
  const int kthi = min(ks * 16 + 15, min(((int)bmx) >> 6, T / 64 - 1));

  f32x4 o[4];
#pragma unroll
  for (int c = 0; c < 4; ++c) o[c] = (f32x4){0, 0, 0, 0};
  float lacc = 0.0f;

  const int rq = tid >> 3, cb = (tid & 7) * 8;

#pragma unroll 1
  for (int kt = ktlo; kt <= kthi; ++kt) {
    const int j0 = kt * 64;
    __syncthreads();   // prior-iter Ks/Vt reads done
#pragma unroll
    for (int it = 0; it < 2; ++it) {
      int rr = it * 32 + rq;
      *(bf16x8*)&Ks[rr * 72 + cb] =
          *(const bf16x8*)&qkvb[(size_t)(b * T + j0 + rr) * 1536 + 512 + h * 64 + cb];
      *(bf16x8*)&Vt[rr * 72 + cb] =
          *(const bf16x8*)&Vtg[(size_t)(bh * 64 + rr) * T + j0 + cb];
    }
    __syncthreads();

    // ---- S^T = K Q^T (log2 domain): regs = j, lane = i ----
    f32x4 s[4];
#pragma unroll
    for (int nc = 0; nc < 4; ++nc) {
      const short* kb = &Ks[(nc * 16 + l15) * 72 + quad * 8];
      f32x4 a = (f32x4){0, 0, 0, 0};
      a = __builtin_amdgcn_mfma_f32_16x16x32_bf16(*(const bf16x8*)&kb[0],  aQ0, a, 0, 0, 0);
      a = __builtin_amdgcn_mfma_f32_16x16x32_bf16(*(const bf16x8*)&kb[32], aQ1, a, 0, 0, 0);
      s[nc] = a;
    }

    // interior tile for every row of this wave?  (wave-uniform branch)
    const int clean = (bli < j0) & (bli + widi > j0 + 63) &
                      ((ali > j0 + 63) | (ali + 1 < j0));
    if (__all(clean)) {
      // ---- fast path: p = exp2(s) ----
#pragma unroll
      for (int nc = 0; nc < 4; ++nc) {
        float p0 = EXP2F(s[nc][0]);
        float p1 = EXP2F(s[nc][1]);
        float p2 = EXP2F(s[nc][2]);
        float p3 = EXP2F(s[nc][3]);
        lacc += (p0 + p1) + (p2 + p3);
        int2v pk;
        pk[0] = (int)pkhu(p0, p1);
        pk[1] = (int)pkhu(p2, p3);
        *(int2v*)&Ps[wave][l15 * 72 + nc * 16 + quad * 4] = pk;
      }
    } else {
      // ---- slow path: weights + mask ----
      const int dq  = j0 + quad * 4 - bli;
      const int dq2 = j0 + quad * 4 - ali;
#pragma unroll
      for (int nc = 0; nc < 4; ++nc) {
        const int dn = dq + nc * 16, d2n = dq2 + nc * 16;
        float pr[4];
#pragma unroll
        for (int r = 0; r < 4; ++r) {
          int d = dn + r, d2 = d2n + r;
          float e  = (d == 0) ? wbl : ((d == widi) ? wbr : 0.0f);
          float aw = (d2 == 0) ? a1 : ((d2 == 1) ? afr : 0.0f);
          float w = 1.0f + e + aw;
          float v = s[nc][r] * w;                    // log2 domain
          v = ((unsigned)d <= widu) ? v : -115.0f;
          float p = EXP2F(v);
          lacc += p;
          pr[r] = p;
        }
        int2v pk;
        pk[0] = (int)pkhu(pr[0], pr[1]);
        pk[1] = (int)pkhu(pr[2], pr[3]);
        *(int2v*)&Ps[wave][l15 * 72 + nc * 16 + quad * 4] = pk;
      }
    }
    // wave-private Ps: no barrier needed

    // ---- O^T += V^T P^T ----
    bf16x8 bP0 = *(const bf16x8*)&Ps[wave][l15 * 72 + quad * 8];
    bf16x8 bP1 = *(const bf16x8*)&Ps[wave][l15 * 72 + 32 + quad * 8];
#pragma unroll
    for (int nc2 = 0; nc2 < 4; ++nc2) {
      const short* vb = &Vt[(nc2 * 16 + l15) * 72 + quad * 8];
      o[nc2] = __builtin_amdgcn_mfma_f32_16x16x32_bf16(
          *(const bf16x8*)&vb[0],  bP0, o[nc2], 0, 0, 0);
      o[nc2] = __builtin_amdgcn_mfma_f32_16x16x32_bf16(
          *(const bf16x8*)&vb[32], bP1, o[nc2], 0, 0, 0);
    }
  }

  // l: sum the 4 quads holding the same row i
  lacc += __shfl_xor(lacc, 16);
  lacc += __shfl_xor(lacc, 32);
  if (lane < 16)
    lpart[ks * NT + bh * T + i] = lacc;

  // O^T epilogue (bf16): lane = row i, regs = channels c
  size_t ob = (size_t)ks * (B * T * E) + (size_t)(b * T + i) * E + h * 64;
#pragma unroll
  for (int nc2 = 0; nc2 < 4; ++nc2) {
    int2v pk;
    pk[0] = (int)pk2bf(o[nc2][0], o[nc2][1]);
    pk[1] = (int)pk2bf(o[nc2][2], o[nc2][3]);
    *(int2v*)&Opart[ob + nc2 * 16 + quad * 4] = pk;
  }
}

// =====================================================================
// attn = (O0 + O1) / (l0 + l1), bf16 in/out. 8 elems/thread.
// =====================================================================
__global__ __launch_bounds__(256) void combine_attn(
    const short* __restrict__ Opart, const float* __restrict__ lpart,
    short* __restrict__ attnb)
{
  int base = (blockIdx.x * 256 + threadIdx.x) * 8;
  int row = base >> 9;            // / 512
  int c = base & 511;
  int h = c >> 6;
  int b = row >> 11;              // / T
  int i = row & (T - 1);
  int lidx = ((b << 3) + h) * T + i;
  float inv = 1.0f / (lpart[lidx] + lpart[NT + lidx]);
  bf16x8 o0 = *(const bf16x8*)&Opart[base];
  bf16x8 o1 = *(const bf16x8*)&Opart[(size_t)(B * T * E) + base];
  int4v ov;
#pragma unroll
  for (int j = 0; j < 4; ++j) {
    float a = (bf2f(o0[2 * j]) + bf2f(o1[2 * j])) * inv;
    float bfv = (bf2f(o0[2 * j + 1]) + bf2f(o1[2 * j + 1])) * inv;
    ov[j] = (int)pk2bf(a, bfv);
  }
  *(int4v*)&attnb[base] = ov;
}

// =====================================================================
// out GEMM (bf16 MFMA): out[4096][512] = attnb @ w_out + b_out (fp32).
// Tile 64x128, BK=32, 4 waves 2x2 (wave 32x64). Grid (4, 64) = 256.
// =====================================================================
__global__ __launch_bounds__(256) void out_gemm_bf16(
    const short* __restrict__ Ab, const short* __restrict__ wT,
    const float* __restrict__ bias, float* __restrict__ Co)
{
  __shared__ __align__(16) short As[64 * 40];
  __shared__ __align__(16) short Bt[128 * 40];

  const int tid = threadIdx.x;
  const int wave = tid >> 6, lane = tid & 63;
  const int quad = lane >> 4, l15 = lane & 15;
  const int wm = wave >> 1, wn = wave & 1;
  const int m0 = blockIdx.y * 64, n0 = blockIdx.x * 128;

  f32x4 acc[2][4];
#pragma unroll
  for (int mi = 0; mi < 2; ++mi)
#pragma unroll
    for (int ni = 0; ni < 4; ++ni) acc[mi][ni] = (f32x4){0, 0, 0, 0};

  const int ar = tid >> 2, akc = (tid & 3) * 8;      // A: 64 rows x 32
  const int br_ = tid >> 1, bkc = (tid & 1) * 16;    // B: 128 rows x 32

#pragma unroll 1
  for (int k0 = 0; k0 < E; k0 += 32) {
    __syncthreads();
    *(bf16x8*)&As[ar * 40 + akc] =
        *(const bf16x8*)&Ab[(size_t)(m0 + ar) * 512 + k0 + akc];
    *(bf16x8*)&Bt[br_ * 40 + bkc] =
        *(const bf16x8*)&wT[(size_t)(n0 + br_) * 512 + k0 + bkc];
    *(bf16x8*)&Bt[br_ * 40 + bkc + 8] =
        *(const bf16x8*)&wT[(size_t)(n0 + br_) * 512 + k0 + bkc + 8];
    __syncthreads();

    bf16x8 aA[2], bB[4];
#pragma unroll
    for (int mi = 0; mi < 2; ++mi)
      aA[mi] = *(const bf16x8*)&As[(wm * 32 + mi * 16 + l15) * 40 + quad * 8];
#pragma unroll
    for (int ni = 0; ni < 4; ++ni)
      bB[ni] = *(const bf16x8*)&Bt[(wn * 64 + ni * 16 + l15) * 40 + quad * 8];
#pragma unroll
    for (int mi = 0; mi < 2; ++mi)
#pragma unroll
      for (int ni = 0; ni < 4; ++ni)
        acc[mi][ni] = __builtin_amdgcn_mfma_f32_16x16x32_bf16(
            aA[mi], bB[ni], acc[mi][ni], 0, 0, 0);
  }

#pragma unroll
  for (int mi = 0; mi < 2; ++mi)
#pragma unroll
    for (int ni = 0; ni < 4; ++ni)
#pragma unroll
      for (int r = 0; r < 4; ++r) {
        int row = m0 + wm * 32 + mi * 16 + quad * 4 + r;
        int col = n0 + wn * 64 + ni * 16 + l15;
        Co[(size_t)row * 512 + col] = acc[mi][ni][r] + bias[col];
      }
}

// =====================================================================
extern "C" void kernel_launch(void* const* d_in, const int* in_sizes, int n_in,
                              void* d_out, int out_size, void* d_ws, size_t ws_size,
                              hipStream_t stream)
{
  const float* x     = (const float*)d_in[0];
  const float* w_qkv = (const float*)d_in[1];
  const float* b_qkv = (const float*)d_in[2];
  const float* w_od  = (const float*)d_in[3];
  const float* b_od  = (const float*)d_in[4];
  const float* w_out = (const float*)d_in[5];
  const float* b_out = (const float*)d_in[6];
  float* out = (float*)d_out;

  char* w = (char*)d_ws;
  short* xb    = (short*)w;  w += (size_t)B * T * E * 2;          // 4 MB
  short* wTq   = (short*)w;  w += (size_t)E * 3 * E * 2;          // 1.5 MB
  short* wTo   = (short*)w;  w += (size_t)E * E * 2;              // 0.5 MB
  short* qkvb  = (short*)w;  w += (size_t)B * T * 3 * E * 2;      // 12.6 MB
  short* Vtg   = (short*)w;  w += (size_t)B * T * E * 2;          // 4 MB
  float* Wc    = (float*)w;  w += (size_t)E * 16 * 4;             // 32 KB
  float* bc    = (float*)w;  w += 256;
  float* prm   = (float*)w;  w += (size_t)7 * NT * 4;             // 896 KB
  short* Opart = (short*)w;  w += (size_t)2 * B * T * E * 2;      // 8.4 MB
  float* lpart = (float*)w;  w += (size_t)2 * NT * 4;             // 256 KB
  short* attnb = (short*)w;  w += (size_t)B * T * E * 2;          // 4 MB

  // 1) fused prep: casts + transposes + combined od weights
  prep_all<<<dim3(3105), 256, 0, stream>>>(
      x, w_qkv, b_qkv, w_od, b_od, xb, wTq, wTo, w_out, Wc, bc);

  // 2) qkv GEMM (Q pre-scaled by SCALE*log2e; V written transposed)
  qkv_gemm_bf16<<<dim3(3 * E / 128, B * T / 128), 256, 0, stream>>>(
      xb, wTq, b_qkv, qkvb, Vtg);

  // 3) window params (fp32 exact)
  od_params<<<dim3(B * T / 16), 256, 0, stream>>>(x, Wc, bc, prm);

  // 4) attention (fast/slow path flash, K-split 2-way)
  flash_attn_mfma4<<<dim3(T / 64, BH, 2), 256, 0, stream>>>(
      qkvb, Vtg, prm, Opart, lpart);

  // 5) combine partials -> attn bf16
  combine_attn<<<dim3(B * T * E / 2048), 256, 0, stream>>>(Opart, lpart, attnb);

  // 6) out = attn @ w_out + b_out
  out_gemm_bf16<<<dim3(E / 128, B * T / 64), 256, 0, stream>>>(
      attnb, wTo, b_out, out);
}

// Round 7
// 163.561 us; speedup vs baseline: 1.2095x; 1.1202x over previous
//
#include <hip/hip_runtime.h>
#include <math.h>

typedef float vf4 __attribute__((ext_vector_type(4)));
typedef float f32x4 __attribute__((ext_vector_type(4)));
typedef short bf16x8 __attribute__((ext_vector_type(8)));
typedef short short4v __attribute__((ext_vector_type(4)));
typedef int int2v __attribute__((ext_vector_type(2)));
typedef int int4v __attribute__((ext_vector_type(4)));

constexpr int B = 2, T = 2048, E = 512, NH = 8, HD = 64;
constexpr int BH = B * NH;            // 16
constexpr int NT = BH * T;            // 32768
constexpr int KSPLIT = 4;
constexpr float SCALE = 0.125f;       // HD^-0.5
constexpr float LOG2E = 1.44269504088896f;
constexpr float QSC = SCALE * LOG2E;  // folded into Q -> S in log2 domain

static __device__ __forceinline__ short f2bf(float f) {
  unsigned u = __float_as_uint(f);
  unsigned r = (u + 0x7fffu + ((u >> 16) & 1u)) >> 16;   // RNE
  return (short)r;
}
static __device__ __forceinline__ unsigned pk2bf(float a, float b) {  // RNE pack
  unsigned lo = (unsigned)(unsigned short)f2bf(a);
  unsigned hi = (unsigned)(unsigned short)f2bf(b);
  return lo | (hi << 16);
}
// cheap half-up bf16 pack (unbiased, <=2^-9 rel err) — inner-loop use
static __device__ __forceinline__ unsigned pkhu(float a, float b) {
  unsigned ua = __float_as_uint(a) + 0x8000u;
  unsigned ub = __float_as_uint(b) + 0x8000u;
  return __builtin_amdgcn_perm(ub, ua, 0x07060302u);  // [ua.hi16 | ub.hi16]
}
#if __has_builtin(__builtin_amdgcn_exp2f)
#define EXP2F(x) __builtin_amdgcn_exp2f(x)
#else
#define EXP2F(x) exp2f(x)
#endif
static __device__ __forceinline__ float bf2f(short s) {
  return __uint_as_float(((unsigned)(unsigned short)s) << 16);
}

// =====================================================================
// prep_all: fused cast_x | w_qkv^T | w_out^T | w_comb.  Grid 3105 blocks.
// =====================================================================
__global__ __launch_bounds__(256) void prep_all(
    const float* __restrict__ x, const float* __restrict__ w_qkv,
    const float* __restrict__ b_qkv, const float* __restrict__ w_od,
    const float* __restrict__ b_od,
    short* __restrict__ xb, short* __restrict__ wTq, short* __restrict__ wTo,
    const float* __restrict__ w_out, float* __restrict__ Wc,
    float* __restrict__ bc)
{
  __shared__ float sh[8464];
  const int bid = blockIdx.x;
  const int tid = threadIdx.x;

  if (bid < 2048) {                       // ---- cast x -> bf16
    int idx = (bid * 256 + tid) * 4;
    vf4 v = *(const vf4*)&x[idx];
    short4v o;
    o[0] = f2bf(v[0]); o[1] = f2bf(v[1]); o[2] = f2bf(v[2]); o[3] = f2bf(v[3]);
    *(short4v*)&xb[idx] = o;
  } else if (bid < 3072) {                // ---- transpose-cast weights
    const float* w; short* wT; int N, t;
    if (bid < 2816) { t = bid - 2048; w = w_qkv; wT = wTq; N = 1536; }
    else            { t = bid - 2816; w = w_out; wT = wTo; N = 512; }
    float (*tt)[33] = (float(*)[33])sh;
    const int k0 = (t & 15) * 32;
    const int n0 = (t >> 4) * 32;
    const int c = tid & 31, r = tid >> 5;  // r: 0..7
#pragma unroll
    for (int p = 0; p < 4; ++p)
      tt[r + p * 8][c] = w[(size_t)(k0 + r + p * 8) * N + n0 + c];
    __syncthreads();
#pragma unroll
    for (int p = 0; p < 4; ++p)
      wT[(size_t)(n0 + r + p * 8) * 512 + k0 + c] = f2bf(tt[c][r + p * 8]);
  } else {                                // ---- w_comb
    float* Lod = sh;                 // 512*16
    float (*pb)[17] = (float(*)[17])(sh + 8192);
    const int bx = bid - 3072;       // 0..32
#pragma unroll
    for (int p = 0; p < 8; ++p) {
      int idx = (p * 256 + tid) * 4;
      *(vf4*)&Lod[idx] = *(const vf4*)&w_od[idx];
    }
    __syncthreads();
    if (bx < 32) {
      const int k = bx * 16 + (tid >> 4);
      const int c = tid & 15;
      float s = 0.0f;
      for (int m = 0; m < E; m += 4) {
        vf4 wq = *(const vf4*)&w_qkv[(size_t)k * 1536 + m];
        s += wq[0] * Lod[(m + 0) * 16 + c] + wq[1] * Lod[(m + 1) * 16 + c]
           + wq[2] * Lod[(m + 2) * 16 + c] + wq[3] * Lod[(m + 3) * 16 + c];
      }
      Wc[k * 16 + c] = s;
    } else {
      const int c = tid & 15, seg = tid >> 4;
      float s = 0.0f;
      for (int m = seg * 32; m < seg * 32 + 32; ++m)
        s += b_qkv[m] * Lod[m * 16 + c];
      pb[seg][c] = s;
      __syncthreads();
      if (tid < 16) {
        float acc = b_od[tid];
#pragma unroll
        for (int g = 0; g < 16; ++g) acc += pb[g][tid];
        bc[tid] = acc;
      }
    }
  }
}

// =====================================================================
// Fused qkv GEMM + od/window-params.  Grid 1024: blocks 0..767 do the
// bf16 MFMA qkv GEMM (128x64 tiles, BK=32); blocks 768..1023 do od.
// Q cols pre-scaled by SCALE*LOG2E; V written TRANSPOSED to Vtg.
// Both halves depend only on prep_all outputs -> safe in one dispatch.
// =====================================================================
__global__ __launch_bounds__(256) void qkv_od(
    const short* __restrict__ xb, const short* __restrict__ wT,
    const float* __restrict__ bias, short* __restrict__ qkvb,
    short* __restrict__ Vtg,
    const float* __restrict__ x, const float* __restrict__ Wc,
    const float* __restrict__ bc, float* __restrict__ prm)
{
  __shared__ __align__(16) short smem_s[16896];   // 33792 B
  const int bid = blockIdx.x;
  const int tid = threadIdx.x;

  if (bid < 768) {
    // ---------------- qkv GEMM 128x64 ----------------
    short* As = smem_s;                 // 128*40
    short* Bt = smem_s + 128 * 40;      // 64*40
    const int wave = tid >> 6, lane = tid & 63;
    const int quad = lane >> 4, l15 = lane & 15;
    const int wm = wave >> 1, wn = wave & 1;
    const int bx = bid % 24, by = bid / 24;
    const int m0 = by * 128, n0 = bx * 64;

    f32x4 acc[4][2];
#pragma unroll
    for (int mi = 0; mi < 4; ++mi)
#pragma unroll
      for (int ni = 0; ni < 2; ++ni) acc[mi][ni] = (f32x4){0, 0, 0, 0};

    const int sr = tid >> 1, sc = (tid & 1) * 16;     // A: 128 x 32
    const int br2 = tid >> 2, bk2 = (tid & 3) * 8;    // B: 64 x 32

#pragma unroll 1
    for (int k0 = 0; k0 < E; k0 += 32) {
      __syncthreads();
      *(bf16x8*)&As[sr * 40 + sc] =
          *(const bf16x8*)&xb[(size_t)(m0 + sr) * 512 + k0 + sc];
      *(bf16x8*)&As[sr * 40 + sc + 8] =
          *(const bf16x8*)&xb[(size_t)(m0 + sr) * 512 + k0 + sc + 8];
      *(bf16x8*)&Bt[br2 * 40 + bk2] =
          *(const bf16x8*)&wT[(size_t)(n0 + br2) * 512 + k0 + bk2];
      __syncthreads();

      bf16x8 aA[4], bB[2];
#pragma unroll
      for (int mi = 0; mi < 4; ++mi)
        aA[mi] = *(const bf16x8*)&As[(wm * 64 + mi * 16 + l15) * 40 + quad * 8];
#pragma unroll
      for (int ni = 0; ni < 2; ++ni)
        bB[ni] = *(const bf16x8*)&Bt[(wn * 32 + ni * 16 + l15) * 40 + quad * 8];
#pragma unroll
      for (int mi = 0; mi < 4; ++mi)
#pragma unroll
        for (int ni = 0; ni < 2; ++ni)
          acc[mi][ni] = __builtin_amdgcn_mfma_f32_16x16x32_bf16(
              aA[mi], bB[ni], acc[mi][ni], 0, 0, 0);
    }

#pragma unroll
    for (int mi = 0; mi < 4; ++mi)
#pragma unroll
      for (int ni = 0; ni < 2; ++ni) {
        const int col = n0 + wn * 32 + ni * 16 + l15;
        const int rowb = m0 + wm * 64 + mi * 16 + quad * 4;
        const float bs = bias[col];
        if (col < 1024) {
          const float qs = (col < 512) ? QSC : 1.0f;
#pragma unroll
          for (int r = 0; r < 4; ++r)
            qkvb[(size_t)(rowb + r) * 1536 + col] =
                f2bf((acc[mi][ni][r] + bs) * qs);
        } else {
          // V: transposed write  Vtg[(b*8+h)*64+hd][t]
          const int h = (col - 1024) >> 6, hd = col & 63;
          const int b = rowb >> 11, tt = rowb & 2047;
          int2v pk;
          pk[0] = (int)pk2bf(acc[mi][ni][0] + bs, acc[mi][ni][1] + bs);
          pk[1] = (int)pk2bf(acc[mi][ni][2] + bs, acc[mi][ni][3] + bs);
          *(int2v*)&Vtg[(size_t)(((b << 3) + h) * 64 + hd) * T + tt] = pk;
        }
      }
  } else {
    // ---------------- od + window params (fp32 exact) ----------------
    float* Lod = (float*)smem_s;            // 8192 floats (Wc staged)
    float* ods = ((float*)smem_s) + 8192;   // 16x16
    const int obx = bid - 768;
#pragma unroll
    for (int p = 0; p < 8; ++p) {
      int idx = (p * 256 + tid) * 4;
      *(vf4*)&Lod[idx] = *(const vf4*)&Wc[idx];
    }
    __syncthreads();

    const int r = tid >> 4, c = tid & 15;
    const int row = obx * 16 + r;
    float sum = bc[c];
    const float* qr = x + (size_t)row * E;
    for (int k = 0; k < E; k += 4) {
      vf4 q = *(const vf4*)&qr[k];
      sum += q[0] * Lod[(k + 0) * 16 + c]
           + q[1] * Lod[(k + 1) * 16 + c]
           + q[2] * Lod[(k + 2) * 16 + c]
           + q[3] * Lod[(k + 3) * 16 + c];
    }
    ods[r * 16 + c] = sum;
    __syncthreads();

    if (tid < 128) {
      const int rr = tid >> 3, h = tid & 7;
      const int grow = obx * 16 + rr;
      const int b = grow / T, i = grow % T;
      float o = ods[rr * 16 + h];
      float d = ods[rr * 16 + h + 8];
      float offset   = tanhf(o) * (float)T;
      float duration = (float)T / (1.0f + expf(-d));
      float anchor = (float)i + offset;
      float start = anchor - duration;
      float end   = anchor + duration;
      float bl = floorf(start);
      float br = ceilf(end);
      float al = floorf(anchor);
      float wbl = bl - start;
      float wbr = end - br;
      float af  = anchor - al;
      float rsc = 1.0f;
      if (br < 0.0f || bl > (float)(T - 1)) {
        bl = 0.0f; br = (float)(T - 1);
        wbl = 0.0f; wbr = 0.0f; al = -5.0f; af = 0.0f;
        rsc = 0.0f;
      }
      int idx = (b * NH + h) * T + i;
      prm[0 * NT + idx] = bl;
      prm[1 * NT + idx] = br;
      prm[2 * NT + idx] = wbl;
      prm[3 * NT + idx] = wbr;
      prm[4 * NT + idx] = al;
      prm[5 * NT + idx] = af;
      prm[6 * NT + idx] = rsc;
    }
  }
}

// =====================================================================
// MFMA flash attention: transposed-S, log2-domain, K-split 4-way,
// double-buffered K/V staging (prefetch to VGPR during compute,
// ONE barrier per tile). Fast/slow softmax paths. Opart bf16.
// =====================================================================
__global__ __launch_bounds__(256, 4) void flash_attn_mfma5(
    const short* __restrict__ qkvb, const short* __restrict__ Vtg,
    const float* __restrict__ prm,
    short* __restrict__ Opart, float* __restrict__ lpart)
{
  __shared__ __align__(16) short Ks[2][64 * 72];
  __shared__ __align__(16) short Vt[2][64 * 72];
  __shared__ __align__(16) short Ps[4][16 * 72];
  __shared__ float u_s[8];

  const int tid = threadIdx.x;
  const int wave = tid >> 6, lane = tid & 63;
  const int quad = lane >> 4, l15 = lane & 15;
  const int qt = blockIdx.x, bh = blockIdx.y, ks = blockIdx.z;
  const int b = bh >> 3, h = bh & 7;
  const int i0 = qt * 64;
  const int i = i0 + wave * 16 + l15;          // this lane's query row

  const int pidx = bh * T + i;
  float blf = prm[0 * NT + pidx];
  float brf = prm[1 * NT + pidx];
  float wbl = prm[2 * NT + pidx];
  float wbr = prm[3 * NT + pidx];
  float alf = prm[4 * NT + pidx];
  float afr = prm[5 * NT + pidx];
  float rsc = prm[6 * NT + pidx];
  const int bli = (int)blf, widi = (int)brf - bli, ali = (int)alf;
  const unsigned widu = (unsigned)widi;
  const float a1 = 1.0f - afr;

  // Q fragment (B-frag: lane = i, regs = hd); zeroed for degenerate rows
  bf16x8 aQ0, aQ1;
  {
    size_t bq = (size_t)(b * T + i) * 1536 + h * 64;
    aQ0 = *(const bf16x8*)&qkvb[bq + quad * 8];
    aQ1 = *(const bf16x8*)&qkvb[bq + 32 + quad * 8];
    if (rsc == 0.0f) {
      bf16x8 z = {0, 0, 0, 0, 0, 0, 0, 0};
      aQ0 = z; aQ1 = z;
    }
  }

  // block union of windows -> K-tile range for this split
  float bmn = blf, bmx = brf;
#pragma unroll
  for (int d = 1; d < 64; d <<= 1) {
    bmn = fminf(bmn, __shfl_xor(bmn, d));
    bmx = fmaxf(bmx, __shfl_xor(bmx, d));
  }
  if (lane == 0) { u_s[wave * 2] = bmn; u_s[wave * 2 + 1] = bmx; }
  __syncthreads();
  bmn = fminf(fminf(u_s[0], u_s[2]), fminf(u_s[4], u_s[6]));
  bmx = fmaxf(fmaxf(u_s[1], u_s[3]), fmaxf(u_s[5], u_s[7]));
  const int ktlo = max(ks * 8, max(((int)bmn) >> 6, 0));
  const int kthi = min(ks * 8 + 7, min(((int)bmx) >> 6, T / 64 - 1));

  f32x4 o[4];
#pragma unroll
  for (int c = 0; c < 4; ++c) o[c] = (f32x4){0, 0, 0, 0};
  float lacc = 0.0f;

  const int rq = tid >> 3, cb = (tid & 7) * 8;
  const short* kbase = qkvb + (size_t)b * T * 1536 + 512 + h * 64 + cb;
  const short* vbase = Vtg + (size_t)bh * 64 * T + cb;

  // preload first tile
  bf16x8 kr0, kr1, vr0, vr1;
  if (ktlo <= kthi) {
    const int j0 = ktlo * 64;
    kr0 = *(const bf16x8*)&kbase[(size_t)(j0 + rq) * 1536];
    kr1 = *(const bf16x8*)&kbase[(size_t)(j0 + 32 + rq) * 1536];
    vr0 = *(const bf16x8*)&vbase[(size_t)rq * T + j0];
    vr1 = *(const bf16x8*)&vbase[(size_t)(32 + rq) * T + j0];
    *(bf16x8*)&Ks[0][rq * 72 + cb] = kr0;
    *(bf16x8*)&Ks[0][(32 + rq) * 72 + cb] = kr1;
    *(bf16x8*)&Vt[0][rq * 72 + cb] = vr0;
    *(bf16x8*)&Vt[0][(32 + rq) * 72 + cb] = vr1;
  }
  __syncthreads();

  int buf = 0;
#pragma unroll 1
  for (int kt = ktlo; kt <= kthi; ++kt) {
    const int j0 = kt * 64;
    // prefetch next tile into registers (overlaps with compute below)
    if (kt < kthi) {
      const int j1 = j0 + 64;
      kr0 = *(const bf16x8*)&kbase[(size_t)(j1 + rq) * 1536];
      kr1 = *(const bf16x8*)&kbase[(size_t)(j1 + 32 + rq) * 1536];
      vr0 = *(const bf16x8*)&vbase[(size_t)rq * T + j1];
      vr1 = *(const bf16x8*)&vbase[(size_t)(32 + rq) * T + j1];
    }

    const short* KsB = Ks[buf];
    const short* VtB = Vt[buf];

    // ---- S^T = K Q^T (log2 domain): regs = j, lane = i ----
    f32x4 s[4];
#pragma unroll
    for (int nc = 0; nc < 4; ++nc) {
      const short* kb = &KsB[(nc * 16 + l15) * 72 + quad * 8];
      f32x4 a = (f32x4){0, 0, 0, 0};
      a = __builtin_amdgcn_mfma_f32_16x16x32_bf16(*(const bf16x8*)&kb[0],  aQ0, a, 0, 0, 0);
      a = __builtin_amdgcn_mfma_f32_16x16x32_bf16(*(const bf16x8*)&kb[32], aQ1, a, 0, 0, 0);
      s[nc] = a;
    }

    // interior tile for every row of this wave? (wave-uniform branch)
    const int clean = (bli < j0) & (bli + widi > j0 + 63) &
                      ((ali > j0 + 63) | (ali + 1 < j0));
    if (__all(clean)) {
      // ---- fast path: p = exp2(s) ----
#pragma unroll
      for (int nc = 0; nc < 4; ++nc) {
        float p0 = EXP2F(s[nc][0]);
        float p1 = EXP2F(s[nc][1]);
        float p2 = EXP2F(s[nc][2]);
        float p3 = EXP2F(s[nc][3]);
        lacc += (p0 + p1) + (p2 + p3);
        int2v pk;
        pk[0] = (int)pkhu(p0, p1);
        pk[1] = (int)pkhu(p2, p3);
        *(int2v*)&Ps[wave][l15 * 72 + nc * 16 + quad * 4] = pk;
      }
    } else {
      // ---- slow path: weights + mask ----
      const int dq  = j0 + quad * 4 - bli;
      const int dq2 = j0 + quad * 4 - ali;
#pragma unroll
      for (int nc = 0; nc < 4; ++nc) {
        const int dn = dq + nc * 16, d2n = dq2 + nc * 16;
        float pr[4];
#pragma unroll
        for (int r = 0; r < 4; ++r) {
          int d = dn + r, d2 = d2n + r;
          float e  = (d == 0) ? wbl : ((d == widi) ? wbr : 0.0f);
          float aw = (d2 == 0) ? a1 : ((d2 == 1) ? afr : 0.0f);
          float w = 1.0f + e + aw;
          float v = s[nc][r] * w;                    // log2 domain
          v = ((unsigned)d <= widu) ? v : -115.0f;
          float p = EXP2F(v);
          lacc += p;
          pr[r] = p;
        }
        int2v pk;
        pk[0] = (int)pkhu(pr[0], pr[1]);
        pk[1] = (int)pkhu(pr[2], pr[3]);
        *(int2v*)&Ps[wave][l15 * 72 + nc * 16 + quad * 4] = pk;
      }
    }
    // wave-private Ps: no barrier needed

    // ---- O^T += V^T P^T ----
    bf16x8 bP0 = *(const bf16x8*)&Ps[wave][l15 * 72 + quad * 8];
    bf16x8 bP1 = *(const bf16x8*)&Ps[wave][l15 * 72 + 32 + quad * 8];
#pragma unroll
    for (int nc2 = 0; nc2 < 4; ++nc2) {
      const short* vb = &VtB[(nc2 * 16 + l15) * 72 + quad * 8];
      o[nc2] = __builtin_amdgcn_mfma_f32_16x16x32_bf16(
          *(const bf16x8*)&vb[0],  bP0, o[nc2], 0, 0, 0);
      o[nc2] = __builtin_amdgcn_mfma_f32_16x16x32_bf16(
          *(const bf16x8*)&vb[32], bP1, o[nc2], 0, 0, 0);
    }

    // ---- write prefetched tile to alternate buffer; ONE barrier ----
    if (kt < kthi) {
      short* Kn = Ks[buf ^ 1];
      short* Vn = Vt[buf ^ 1];
      *(bf16x8*)&Kn[rq * 72 + cb] = kr0;
      *(bf16x8*)&Kn[(32 + rq) * 72 + cb] = kr1;
      *(bf16x8*)&Vn[rq * 72 + cb] = vr0;
      *(bf16x8*)&Vn[(32 + rq) * 72 + cb] = vr1;
      __syncthreads();
      buf ^= 1;
    }
  }

  // l: sum the 4 quads holding the same row i
  lacc += __shfl_xor(lacc, 16);
  lacc += __shfl_xor(lacc, 32);
  if (lane < 16)
    lpart[ks * NT + bh * T + i] = lacc;

  // O^T epilogue (bf16): lane = row i, regs = channels c
  size_t ob = (size_t)ks * (B * T * E) + (size_t)(b * T + i) * E + h * 64;
#pragma unroll
  for (int nc2 = 0; nc2 < 4; ++nc2) {
    int2v pk;
    pk[0] = (int)pk2bf(o[nc2][0], o[nc2][1]);
    pk[1] = (int)pk2bf(o[nc2][2], o[nc2][3]);
    *(int2v*)&Opart[ob + nc2 * 16 + quad * 4] = pk;
  }
}

// =====================================================================
// attn = sum_s O_s / sum_s l_s, bf16 in/out. 8 elems/thread.
// =====================================================================
__global__ __launch_bounds__(256) void combine_attn(
    const short* __restrict__ Opart, const float* __restrict__ lpart,
    short* __restrict__ attnb)
{
  int base = (blockIdx.x * 256 + threadIdx.x) * 8;
  int row = base >> 9;            // / 512
  int c = base & 511;
  int h = c >> 6;
  int b = row >> 11;              // / T
  int i = row & (T - 1);
  int lidx = ((b << 3) + h) * T + i;
  float l = (lpart[lidx] + lpart[NT + lidx]) +
            (lpart[2 * NT + lidx] + lpart[3 * NT + lidx]);
  float inv = 1.0f / l;
  bf16x8 o0 = *(const bf16x8*)&Opart[base];
  bf16x8 o1 = *(const bf16x8*)&Opart[(size_t)(B * T * E) + base];
  bf16x8 o2 = *(const bf16x8*)&Opart[(size_t)(2 * B * T * E) + base];
  bf16x8 o3 = *(const bf16x8*)&Opart[(size_t)(3 * B * T * E) + base];
  int4v ov;
#pragma unroll
  for (int j = 0; j < 4; ++j) {
    float a = ((bf2f(o0[2 * j]) + bf2f(o1[2 * j])) +
               (bf2f(o2[2 * j]) + bf2f(o3[2 * j]))) * inv;
    float bb = ((bf2f(o0[2 * j + 1]) + bf2f(o1[2 * j + 1])) +
                (bf2f(o2[2 * j + 1]) + bf2f(o3[2 * j + 1]))) * inv;
    ov[j] = (int)pk2bf(a, bb);
  }
  *(int4v*)&attnb[base] = ov;
}

// =====================================================================
// out GEMM (bf16 MFMA): out[4096][512] = attnb @ w_out + b_out (fp32).
// Tile 64x64, BK=32, 4 waves 2x2. Grid (8, 64) = 512 blocks.
// =====================================================================
__global__ __launch_bounds__(256) void out_gemm_bf16(
    const short* __restrict__ Ab, const short* __restrict__ wT,
    const float* __restrict__ bias, float* __restrict__ Co)
{
  __shared__ __align__(16) short As[64 * 40];
  __shared__ __align__(16) short Bt[64 * 40];

  const int tid = threadIdx.x;
  const int wave = tid >> 6, lane = tid & 63;
  const int quad = lane >> 4, l15 = lane & 15;
  const int wm = wave >> 1, wn = wave & 1;
  const int m0 = blockIdx.y * 64, n0 = blockIdx.x * 64;

  f32x4 acc[2][2];
#pragma unroll
  for (int mi = 0; mi < 2; ++mi)
#pragma unroll
    for (int ni = 0; ni < 2; ++ni) acc[mi][ni] = (f32x4){0, 0, 0, 0};

  const int ar = tid >> 2, akc = (tid & 3) * 8;

#pragma unroll 1
  for (int k0 = 0; k0 < E; k0 += 32) {
    __syncthreads();
    *(bf16x8*)&As[ar * 40 + akc] =
        *(const bf16x8*)&Ab[(size_t)(m0 + ar) * 512 + k0 + akc];
    *(bf16x8*)&Bt[ar * 40 + akc] =
        *(const bf16x8*)&wT[(size_t)(n0 + ar) * 512 + k0 + akc];
    __syncthreads();

    bf16x8 aA[2], bB[2];
#pragma unroll
    for (int mi = 0; mi < 2; ++mi)
      aA[mi] = *(const bf16x8*)&As[(wm * 32 + mi * 16 + l15) * 40 + quad * 8];
#pragma unroll
    for (int ni = 0; ni < 2; ++ni)
      bB[ni] = *(const bf16x8*)&Bt[(wn * 32 + ni * 16 + l15) * 40 + quad * 8];
#pragma unroll
    for (int mi = 0; mi < 2; ++mi)
#pragma unroll
      for (int ni = 0; ni < 2; ++ni)
        acc[mi][ni] = __builtin_amdgcn_mfma_f32_16x16x32_bf16(
            aA[mi], bB[ni], acc[mi][ni], 0, 0, 0);
  }

#pragma unroll
  for (int mi = 0; mi < 2; ++mi)
#pragma unroll
    for (int ni = 0; ni < 2; ++ni)
#pragma unroll
      for (int r = 0; r < 4; ++r) {
        int row = m0 + wm * 32 + mi * 16 + quad * 4 + r;
        int col = n0 + wn * 32 + ni * 16 + l15;
        Co[(size_t)row * 512 + col] = acc[mi][ni][r] + bias[col];
      }
}

// =====================================================================
extern "C" void kernel_launch(void* const* d_in, const int* in_sizes, int n_in,
                              void* d_out, int out_size, void* d_ws, size_t ws_size,
                              hipStream_t stream)
{
  const float* x     = (const float*)d_in[0];
  const float* w_qkv = (const float*)d_in[1];
  const float* b_qkv = (const float*)d_in[2];
  const float* w_od  = (const float*)d_in[3];
  const float* b_od  = (const float*)d_in[4];
  const float* w_out = (const float*)d_in[5];
  const float* b_out = (const float*)d_in[6];
  float* out = (float*)d_out;

  char* w = (char*)d_ws;
  short* xb    = (short*)w;  w += (size_t)B * T * E * 2;           // 4 MB
  short* wTq   = (short*)w;  w += (size_t)E * 3 * E * 2;           // 1.5 MB
  short* wTo   = (short*)w;  w += (size_t)E * E * 2;               // 0.5 MB
  short* qkvb  = (short*)w;  w += (size_t)B * T * 3 * E * 2;       // 12.6 MB
  short* Vtg   = (short*)w;  w += (size_t)B * T * E * 2;           // 4 MB
  float* Wc    = (float*)w;  w += (size_t)E * 16 * 4;              // 32 KB
  float* bc    = (float*)w;  w += 256;
  float* prm   = (float*)w;  w += (size_t)7 * NT * 4;              // 896 KB
  short* Opart = (short*)w;  w += (size_t)KSPLIT * B * T * E * 2;  // 16.8 MB
  float* lpart = (float*)w;  w += (size_t)KSPLIT * NT * 4;         // 512 KB
  short* attnb = (short*)w;  w += (size_t)B * T * E * 2;           // 4 MB

  // 1) fused prep: casts + transposes + combined od weights
  prep_all<<<dim3(3105), 256, 0, stream>>>(
      x, w_qkv, b_qkv, w_od, b_od, xb, wTq, wTo, w_out, Wc, bc);

  // 2) fused qkv GEMM (V transposed, Q pre-scaled) + od/window params
  qkv_od<<<dim3(1024), 256, 0, stream>>>(
      xb, wTq, b_qkv, qkvb, Vtg, x, Wc, bc, prm);

  // 3) attention (double-buffered flash, K-split 4-way)
  flash_attn_mfma5<<<dim3(T / 64, BH, KSPLIT), 256, 0, stream>>>(
      qkvb, Vtg, prm, Opart, lpart);

  // 4) combine partials -> attn bf16
  combine_attn<<<dim3(B * T * E / 2048), 256, 0, stream>>>(Opart, lpart, attnb);

  // 5) out = attn @ w_out + b_out
  out_gemm_bf16<<<dim3(E / 64, B * T / 64), 256, 0, stream>>>(
      attnb, wTo, b_out, out);
}